// Round 1
// baseline (331.021 us; speedup 1.0000x reference)
//
#include <hip/hip_runtime.h>
#include <stdint.h>

// ---- problem constants ----
#define Bz 8
#define Tz 1024
#define Cz 768
#define Hz 8
#define Dz 96
#define BHz 64            // Bz*Hz
#define Mz 8192           // Bz*Tz
#define Kz 768

typedef __bf16 bf16x8 __attribute__((ext_vector_type(8)));
typedef unsigned short u16x8 __attribute__((ext_vector_type(8)));
typedef float f32x4 __attribute__((ext_vector_type(4)));

__device__ __forceinline__ unsigned short f2bf(float f) {
  union { float f; unsigned int u; } v; v.f = f;
  unsigned int u = v.u;
  return (unsigned short)((u + 0x7fffu + ((u >> 16) & 1u)) >> 16);
}

// ---- cast x (fp32) -> bf16, 4 elems/thread ----
__global__ __launch_bounds__(256) void cast_f32_bf16(const float* __restrict__ in,
                                                     unsigned short* __restrict__ out) {
  int i = (blockIdx.x * 256 + threadIdx.x) * 4;
  float4 v = *(const float4*)(in + i);
  union { unsigned short s[4]; uint2 u; } o;
  o.s[0] = f2bf(v.x); o.s[1] = f2bf(v.y); o.s[2] = f2bf(v.z); o.s[3] = f2bf(v.w);
  *(uint2*)(out + i) = o.u;
}

// ---- transpose + cast: in[R][Cc] fp32 -> out[Cc][R] bf16 ----
__global__ __launch_bounds__(256) void transpose_cast(const float* __restrict__ in,
                                                      unsigned short* __restrict__ out,
                                                      int R, int Cc) {
  __shared__ unsigned short t[64][72];   // pad 72 keeps writes ~2-way
  int bx = blockIdx.x * 64;   // col base of in
  int by = blockIdx.y * 64;   // row base of in
  int tid = threadIdx.x;
#pragma unroll
  for (int i = 0; i < 16; i++) {
    int idx = tid + i * 256;
    int r = idx >> 6, c = idx & 63;
    t[c][r] = f2bf(in[(by + r) * Cc + bx + c]);
  }
  __syncthreads();
#pragma unroll
  for (int i = 0; i < 16; i++) {
    int idx = tid + i * 256;
    int r = idx >> 6, c = idx & 63;
    out[(bx + r) * R + by + c] = t[r][c];
  }
}

// ---- 128x128 MFMA bf16 GEMM, A[M][K] bf16, Bt[N][K] bf16 ----
// MODE 0: epilogue scatters bf16 into qkv [3][64][1024][96]
// MODE 1: epilogue writes fp32 C[M][768]
template <int MODE>
__global__ __launch_bounds__(256)
void gemm128(const unsigned short* __restrict__ A,
             const unsigned short* __restrict__ Bt,
             unsigned short* __restrict__ obf,
             float* __restrict__ of32) {
  __shared__ unsigned short Asm[128 * 40];  // stride 40 (80B = 5*16B): aligned b128, ~2-way banks
  __shared__ unsigned short Bsm[128 * 40];
  const int tid = threadIdx.x;
  const int wave = tid >> 6, lane = tid & 63;
  const int quad = lane >> 4, l16 = lane & 15;
  const int bm = blockIdx.x, bn = blockIdx.y;
  const int wm = (wave >> 1) * 64, wn = (wave & 1) * 64;

  f32x4 zero = {0.f, 0.f, 0.f, 0.f};
  f32x4 acc[4][4];
#pragma unroll
  for (int i = 0; i < 4; i++)
#pragma unroll
    for (int j = 0; j < 4; j++) acc[i][j] = zero;

  const int e0 = wave * 1024 + lane * 8;
  const int e1 = e0 + 512;
  const int r0 = e0 >> 5, c0 = e0 & 31;
  const int r1 = e1 >> 5, c1 = e1 & 31;
  const unsigned short* Ag0 = A + (bm * 128 + r0) * Kz + c0;
  const unsigned short* Ag1 = A + (bm * 128 + r1) * Kz + c1;
  const unsigned short* Bg0 = Bt + (bn * 128 + r0) * Kz + c0;
  const unsigned short* Bg1 = Bt + (bn * 128 + r1) * Kz + c1;

  for (int k0 = 0; k0 < Kz; k0 += 32) {
    uint4 a0 = *(const uint4*)(Ag0 + k0);
    uint4 a1 = *(const uint4*)(Ag1 + k0);
    uint4 b0 = *(const uint4*)(Bg0 + k0);
    uint4 b1 = *(const uint4*)(Bg1 + k0);
    __syncthreads();
    *(uint4*)&Asm[r0 * 40 + c0] = a0;
    *(uint4*)&Asm[r1 * 40 + c1] = a1;
    *(uint4*)&Bsm[r0 * 40 + c0] = b0;
    *(uint4*)&Bsm[r1 * 40 + c1] = b1;
    __syncthreads();
    bf16x8 af[4], bfr[4];
#pragma unroll
    for (int mi = 0; mi < 4; mi++)
      af[mi] = *(const bf16x8*)&Asm[(wm + mi * 16 + l16) * 40 + quad * 8];
#pragma unroll
    for (int ni = 0; ni < 4; ni++)
      bfr[ni] = *(const bf16x8*)&Bsm[(wn + ni * 16 + l16) * 40 + quad * 8];
#pragma unroll
    for (int mi = 0; mi < 4; mi++)
#pragma unroll
      for (int ni = 0; ni < 4; ni++)
        acc[mi][ni] = __builtin_amdgcn_mfma_f32_16x16x32_bf16(af[mi], bfr[ni], acc[mi][ni], 0, 0, 0);
  }

#pragma unroll
  for (int mi = 0; mi < 4; mi++) {
    int row = bm * 128 + wm + mi * 16 + quad * 4;   // multiple of 4; no b-crossing within r
    if (MODE == 0) {
      int b = row >> 10;
      int t = row & 1023;
#pragma unroll
      for (int ni = 0; ni < 4; ni++) {
        int col = bn * 128 + wn + ni * 16 + l16;
        int which = col / 768;
        int cc = col - which * 768;
        int h = cc / 96;
        int d = cc - h * 96;
        int base = ((which * 64 + b * 8 + h) * 1024 + t) * 96 + d;
#pragma unroll
        for (int r = 0; r < 4; r++) obf[base + r * 96] = f2bf(acc[mi][ni][r]);
      }
    } else {
#pragma unroll
      for (int ni = 0; ni < 4; ni++) {
        int col = bn * 128 + wn + ni * 16 + l16;
#pragma unroll
        for (int r = 0; r < 4; r++) of32[(row + r) * 768 + col] = acc[mi][ni][r];
      }
    }
  }
}

// ---- flash attention: 1 block = (b,h) x 64 q-rows; 4 waves x 16 rows; BS=128 ----
__global__ __launch_bounds__(256)
void attn(const unsigned short* __restrict__ qkv, unsigned short* __restrict__ y) {
  const int bh = blockIdx.x;
  const int q0 = blockIdx.y * 64;
  const int tid = threadIdx.x;
  const int wave = tid >> 6, lane = tid & 63;
  const int quad = lane >> 4, l16 = lane & 15;
  const int qw = q0 + wave * 16;
  const int b = bh >> 3, h = bh & 7;

  const unsigned short* Qh = qkv + bh * Tz * Dz;
  const unsigned short* Kh = qkv + (BHz + bh) * Tz * Dz;
  const unsigned short* Vh = qkv + (2 * BHz + bh) * Tz * Dz;

  __shared__ unsigned short Vsm[96 * 136];       // V^T, stride 136 (~2-way banks)
  __shared__ unsigned short Psm[4 * 16 * 136];   // per-wave P tiles
  unsigned short* Pw = Psm + wave * 16 * 136;

  bf16x8 aq[3];
#pragma unroll
  for (int kd = 0; kd < 3; kd++)
    aq[kd] = *(const bf16x8*)(Qh + (qw + l16) * Dz + kd * 32 + quad * 8);

  f32x4 zero = {0.f, 0.f, 0.f, 0.f};
  f32x4 acc_o[6];
#pragma unroll
  for (int i = 0; i < 6; i++) acc_o[i] = zero;
  float NEG = -__builtin_inff();
  float mrow[4] = {NEG, NEG, NEG, NEG};
  float lrow[4] = {0.f, 0.f, 0.f, 0.f};
  const float scale = 0.10206207261596577f;  // 1/sqrt(96)

  for (int s0 = 0; s0 < q0 + 64; s0 += 128) {
    __syncthreads();                 // WAR: prior iter's LDS reads done
    // stage V^T into LDS (tile s0..s0+127, all 96 d)
#pragma unroll
    for (int i = 0; i < 6; i++) {
      int c = tid + i * 256;
      int sl = c / 12;
      int dj = (c - sl * 12) * 8;
      u16x8 v = *(const u16x8*)(Vh + (s0 + sl) * Dz + dj);
#pragma unroll
      for (int j = 0; j < 8; j++) Vsm[(dj + j) * 136 + sl] = v[j];
    }
    __syncthreads();

    const bool active = (s0 < qw + 16);
    if (active) {
      f32x4 sacc[8];
#pragma unroll
      for (int i = 0; i < 8; i++) sacc[i] = zero;
      const int nlim = (qw + 15 - s0) >> 4;   // tiles with any unmasked col
#pragma unroll
      for (int kd = 0; kd < 3; kd++) {
#pragma unroll
        for (int ni = 0; ni < 8; ni++) {
          if (ni <= nlim) {
            bf16x8 bk = *(const bf16x8*)(Kh + (s0 + ni * 16 + l16) * Dz + kd * 32 + quad * 8);
            sacc[ni] = __builtin_amdgcn_mfma_f32_16x16x32_bf16(aq[kd], bk, sacc[ni], 0, 0, 0);
          }
        }
      }
      // scale + causal mask + row max
      float rmax[4] = {NEG, NEG, NEG, NEG};
#pragma unroll
      for (int ni = 0; ni < 8; ni++) {
        int s_abs = s0 + ni * 16 + l16;
#pragma unroll
        for (int r = 0; r < 4; r++) {
          int t_abs = qw + quad * 4 + r;
          float v = (s_abs > t_abs) ? NEG : sacc[ni][r] * scale;
          sacc[ni][r] = v;
          rmax[r] = fmaxf(rmax[r], v);
        }
      }
#pragma unroll
      for (int r = 0; r < 4; r++)
#pragma unroll
        for (int sh = 1; sh < 16; sh <<= 1)
          rmax[r] = fmaxf(rmax[r], __shfl_xor(rmax[r], sh));

      float alpha[4], rsum[4];
#pragma unroll
      for (int r = 0; r < 4; r++) {
        float mnew = fmaxf(mrow[r], rmax[r]);
        alpha[r] = __expf(mrow[r] - mnew);
        mrow[r] = mnew;
        rsum[r] = 0.f;
      }
      // P = exp(S - m), write ALL 8 tiles (masked -> 0) so Pw is fully refreshed
#pragma unroll
      for (int ni = 0; ni < 8; ni++) {
#pragma unroll
        for (int r = 0; r < 4; r++) {
          float p = __expf(sacc[ni][r] - mrow[r]);
          rsum[r] += p;
          Pw[(quad * 4 + r) * 136 + ni * 16 + l16] = f2bf(p);
        }
      }
#pragma unroll
      for (int r = 0; r < 4; r++) {
#pragma unroll
        for (int sh = 1; sh < 16; sh <<= 1) rsum[r] += __shfl_xor(rsum[r], sh);
        lrow[r] = lrow[r] * alpha[r] + rsum[r];
      }
#pragma unroll
      for (int di = 0; di < 6; di++)
#pragma unroll
        for (int r = 0; r < 4; r++) acc_o[di][r] *= alpha[r];
    }
    __syncthreads();                 // P visible (cross-lane), V ready
    if (active) {
      const int klim = (qw + 15 - s0) >> 5;
#pragma unroll
      for (int kc = 0; kc < 4; kc++) {
        if (kc <= klim) {
          bf16x8 ap = *(const bf16x8*)&Pw[l16 * 136 + kc * 32 + quad * 8];
#pragma unroll
          for (int di = 0; di < 6; di++) {
            bf16x8 bv = *(const bf16x8*)&Vsm[(di * 16 + l16) * 136 + kc * 32 + quad * 8];
            acc_o[di] = __builtin_amdgcn_mfma_f32_16x16x32_bf16(ap, bv, acc_o[di], 0, 0, 0);
          }
        }
      }
    }
  }

  float linv[4];
#pragma unroll
  for (int r = 0; r < 4; r++) linv[r] = 1.f / lrow[r];
#pragma unroll
  for (int di = 0; di < 6; di++) {
#pragma unroll
    for (int r = 0; r < 4; r++) {
      int t = qw + quad * 4 + r;
      int d = di * 16 + l16;
      y[(b * Tz + t) * Cz + h * Dz + d] = f2bf(acc_o[di][r] * linv[r]);
    }
  }
}

// ---- workspace layout (bytes) ----
#define OFF_XB   0u
#define OFF_WAT  12582912u            // 8192*768*2
#define OFF_WPT  16121856u            // + 2304*768*2
#define OFF_QKV  17301504u            // + 768*768*2
#define OFF_Y    55050240u            // + 3*64*1024*96*2

extern "C" void kernel_launch(void* const* d_in, const int* in_sizes, int n_in,
                              void* d_out, int out_size, void* d_ws, size_t ws_size,
                              hipStream_t stream) {
  const float* x  = (const float*)d_in[0];
  const float* Wa = (const float*)d_in[1];
  const float* Wp = (const float*)d_in[2];
  float* out = (float*)d_out;
  uint8_t* ws = (uint8_t*)d_ws;
  unsigned short* xb  = (unsigned short*)(ws + OFF_XB);
  unsigned short* Wat = (unsigned short*)(ws + OFF_WAT);
  unsigned short* Wpt = (unsigned short*)(ws + OFF_WPT);
  unsigned short* qkv = (unsigned short*)(ws + OFF_QKV);
  unsigned short* y   = (unsigned short*)(ws + OFF_Y);

  cast_f32_bf16<<<6144, 256, 0, stream>>>(x, xb);
  transpose_cast<<<dim3(36, 12), 256, 0, stream>>>(Wa, Wat, 768, 2304);
  transpose_cast<<<dim3(12, 12), 256, 0, stream>>>(Wp, Wpt, 768, 768);
  gemm128<0><<<dim3(64, 18), 256, 0, stream>>>(xb, Wat, qkv, nullptr);
  attn<<<dim3(64, 16), 256, 0, stream>>>(qkv, y);
  gemm128<1><<<dim3(64, 6), 256, 0, stream>>>(y, Wpt, nullptr, out);
}

// Round 2
// 214.396 us; speedup vs baseline: 1.5440x; 1.5440x over previous
//
#include <hip/hip_runtime.h>
#include <stdint.h>

// ---- problem constants ----
#define Bz 8
#define Tz 1024
#define Cz 768
#define Hz 8
#define Dz 96
#define BHz 64            // Bz*Hz
#define Kz 768

typedef __bf16 bf16x8 __attribute__((ext_vector_type(8)));
typedef unsigned short u16x8 __attribute__((ext_vector_type(8)));
typedef float f32x4 __attribute__((ext_vector_type(4)));

__device__ __forceinline__ unsigned short f2bf(float f) {
  union { float f; unsigned int u; } v; v.f = f;
  unsigned int u = v.u;
  return (unsigned short)((u + 0x7fffu + ((u >> 16) & 1u)) >> 16);
}

// async global->LDS, 16B per lane; LDS dest must be wave-uniform base (+lane*16 implicit)
typedef const __attribute__((address_space(1))) void* gas_ptr;
typedef __attribute__((address_space(3))) void* las_ptr;
__device__ __forceinline__ void gl16(const void* g, void* l) {
  __builtin_amdgcn_global_load_lds((gas_ptr)g, (las_ptr)l, 16, 0, 0);
}

// ---- cast x (fp32) -> bf16, 4 elems/thread ----
__global__ __launch_bounds__(256) void cast_f32_bf16(const float* __restrict__ in,
                                                     unsigned short* __restrict__ out) {
  int i = (blockIdx.x * 256 + threadIdx.x) * 4;
  float4 v = *(const float4*)(in + i);
  union { unsigned short s[4]; uint2 u; } o;
  o.s[0] = f2bf(v.x); o.s[1] = f2bf(v.y); o.s[2] = f2bf(v.z); o.s[3] = f2bf(v.w);
  *(uint2*)(out + i) = o.u;
}

// ---- transpose + cast: in[R][Cc] fp32 -> out[Cc][R] bf16 ----
__global__ __launch_bounds__(256) void transpose_cast(const float* __restrict__ in,
                                                      unsigned short* __restrict__ out,
                                                      int R, int Cc) {
  __shared__ unsigned short t[64][72];
  int bx = blockIdx.x * 64;   // col base of in
  int by = blockIdx.y * 64;   // row base of in
  int tid = threadIdx.x;
#pragma unroll
  for (int i = 0; i < 16; i++) {
    int idx = tid + i * 256;
    int r = idx >> 6, c = idx & 63;
    t[c][r] = f2bf(in[(by + r) * Cc + bx + c]);
  }
  __syncthreads();
#pragma unroll
  for (int i = 0; i < 16; i++) {
    int idx = tid + i * 256;
    int r = idx >> 6, c = idx & 63;
    out[(bx + r) * R + by + c] = t[r][c];
  }
}

// ---- 128x128 MFMA bf16 GEMM with global_load_lds staging (m97 structure) ----
// A[M][K] bf16, Bt[N][K] bf16
// MODE 0: epilogue scatters bf16 into qkv [3][64][1024][96]
// MODE 1: epilogue writes fp32 C[M][768]
template <int MODE>
__global__ __launch_bounds__(256)
void gemm128(const unsigned short* __restrict__ A,
             const unsigned short* __restrict__ Bt,
             unsigned short* __restrict__ obf,
             float* __restrict__ of32) {
  __shared__ unsigned short Asm[128 * 32];  // unpadded: required by global_load_lds lane order
  __shared__ unsigned short Bsm[128 * 32];
  const int tid = threadIdx.x;
  const int wave = tid >> 6, lane = tid & 63;
  const int quad = lane >> 4, l16 = lane & 15;
  const int bm = blockIdx.x, bn = blockIdx.y;
  const int wm = (wave >> 1) * 64, wn = (wave & 1) * 64;

  f32x4 zero = {0.f, 0.f, 0.f, 0.f};
  f32x4 acc[4][4];
#pragma unroll
  for (int i = 0; i < 4; i++)
#pragma unroll
    for (int j = 0; j < 4; j++) acc[i][j] = zero;

  // staging map: wave w issue q covers rows w*32+q*16 .. +15; lane l -> row +(l>>2), k-part (l&3)*8
  const int rr = lane >> 2, c8 = (lane & 3) * 8;
  const unsigned short* Ag0 = A + (size_t)(bm * 128 + wave * 32 + rr) * Kz + c8;
  const unsigned short* Ag1 = Ag0 + 16 * Kz;
  const unsigned short* Bg0 = Bt + (size_t)(bn * 128 + wave * 32 + rr) * Kz + c8;
  const unsigned short* Bg1 = Bg0 + 16 * Kz;
  unsigned short* lA0 = &Asm[wave * 1024];      // elements; bytes = wave*2048
  unsigned short* lA1 = lA0 + 512;
  unsigned short* lB0 = &Bsm[wave * 1024];
  unsigned short* lB1 = lB0 + 512;

  for (int k0 = 0; k0 < Kz; k0 += 32) {
    __syncthreads();                 // WAR: previous frag reads done
    gl16(Ag0 + k0, lA0);
    gl16(Ag1 + k0, lA1);
    gl16(Bg0 + k0, lB0);
    gl16(Bg1 + k0, lB1);
    __syncthreads();                 // drains vmcnt(0) then barrier
    bf16x8 af[4], bfr[4];
#pragma unroll
    for (int mi = 0; mi < 4; mi++)
      af[mi] = *(const bf16x8*)&Asm[(wm + mi * 16 + l16) * 32 + quad * 8];
#pragma unroll
    for (int ni = 0; ni < 4; ni++)
      bfr[ni] = *(const bf16x8*)&Bsm[(wn + ni * 16 + l16) * 32 + quad * 8];
#pragma unroll
    for (int mi = 0; mi < 4; mi++)
#pragma unroll
      for (int ni = 0; ni < 4; ni++)
        acc[mi][ni] = __builtin_amdgcn_mfma_f32_16x16x32_bf16(af[mi], bfr[ni], acc[mi][ni], 0, 0, 0);
  }

#pragma unroll
  for (int mi = 0; mi < 4; mi++) {
    int row = bm * 128 + wm + mi * 16 + quad * 4;
    if (MODE == 0) {
      int b = row >> 10;
      int t = row & 1023;
#pragma unroll
      for (int ni = 0; ni < 4; ni++) {
        int col = bn * 128 + wn + ni * 16 + l16;
        int which = col / 768;
        int cc = col - which * 768;
        int h = cc / 96;
        int d = cc - h * 96;
        int base = ((which * 64 + b * 8 + h) * 1024 + t) * 96 + d;
#pragma unroll
        for (int r = 0; r < 4; r++) obf[base + r * 96] = f2bf(acc[mi][ni][r]);
      }
    } else {
#pragma unroll
      for (int ni = 0; ni < 4; ni++) {
        int col = bn * 128 + wn + ni * 16 + l16;
#pragma unroll
        for (int r = 0; r < 4; r++) of32[(row + r) * 768 + col] = acc[mi][ni][r];
      }
    }
  }
}

// ---- flash attention v2: 1 block = (b,h) x 128 q-rows; 4 waves x 32 rows; BS=128 ----
__global__ __launch_bounds__(256, 2)
void attn(const unsigned short* __restrict__ qkv, unsigned short* __restrict__ y) {
  const int bh = blockIdx.x;
  const int q0 = (7 - blockIdx.y) * 128;   // heavy blocks dispatch first
  const int tid = threadIdx.x;
  const int wave = tid >> 6, lane = tid & 63;
  const int quad = lane >> 4, l16 = lane & 15;
  const int qw0 = q0 + wave * 32;          // this wave's 32 q-rows (2 m-tiles)
  const int b = bh >> 3, h = bh & 7;

  const unsigned short* Qh = qkv + bh * Tz * Dz;
  const unsigned short* Kh = qkv + (BHz + bh) * Tz * Dz;
  const unsigned short* Vh = qkv + (2 * BHz + bh) * Tz * Dz;

  __shared__ unsigned short Vsm[96 * 136];       // V^T [d][s], stride 136
  __shared__ unsigned short Psm[4 * 32 * 136];   // per-wave P [32 q][128 s]
  unsigned short* Pw = Psm + wave * 32 * 136;

  bf16x8 aq[2][3];
#pragma unroll
  for (int mi = 0; mi < 2; mi++)
#pragma unroll
    for (int kd = 0; kd < 3; kd++)
      aq[mi][kd] = *(const bf16x8*)(Qh + (qw0 + mi * 16 + l16) * Dz + kd * 32 + quad * 8);

  f32x4 zero = {0.f, 0.f, 0.f, 0.f};
  f32x4 acc_o[2][6];
#pragma unroll
  for (int mi = 0; mi < 2; mi++)
#pragma unroll
    for (int i = 0; i < 6; i++) acc_o[mi][i] = zero;
  const float NEG = -__builtin_inff();
  float mrow[2][4], lrow[2][4];
#pragma unroll
  for (int mi = 0; mi < 2; mi++)
#pragma unroll
    for (int r = 0; r < 4; r++) { mrow[mi][r] = NEG; lrow[mi][r] = 0.f; }
  const float scale = 0.10206207261596577f;  // 1/sqrt(96)

  // conflict-free V^T staging map: lane = s index -> consecutive LDS addresses
  const int sg = tid & 127;
  const int g0 = tid >> 7;
  const unsigned short* Vrow = Vh + sg * Dz;

  for (int s0 = 0; s0 <= q0; s0 += 128) {
    __syncthreads();                 // WAR: prior iter's Vsm reads done
#pragma unroll
    for (int i = 0; i < 6; i++) {
      int g = g0 + 2 * i;            // d-group 0..11
      u16x8 v = *(const u16x8*)(Vrow + s0 * Dz + g * 8);
#pragma unroll
      for (int jj = 0; jj < 8; jj++) Vsm[(g * 8 + jj) * 136 + sg] = v[jj];
    }
    __syncthreads();                 // Vsm ready

    const int srem = qw0 + 31 - s0;              // >= 31 always; srem%32==31
    const int nlim = min(7, srem >> 4);          // last 16-wide s tile with unmasked cols
    const int klim = min(3, srem >> 5);          // last 32-wide PV k chunk

    // ---- S = Q K^T (both m-tiles share K fragments) ----
    f32x4 sacc[2][8];
#pragma unroll
    for (int ni = 0; ni < 8; ni++) {
      if (ni <= nlim) {
        sacc[0][ni] = zero; sacc[1][ni] = zero;
#pragma unroll
        for (int kd = 0; kd < 3; kd++) {
          bf16x8 bk = *(const bf16x8*)(Kh + (s0 + ni * 16 + l16) * Dz + kd * 32 + quad * 8);
          sacc[0][ni] = __builtin_amdgcn_mfma_f32_16x16x32_bf16(aq[0][kd], bk, sacc[0][ni], 0, 0, 0);
          sacc[1][ni] = __builtin_amdgcn_mfma_f32_16x16x32_bf16(aq[1][kd], bk, sacc[1][ni], 0, 0, 0);
        }
      }
    }

    // ---- online softmax per m-tile; P written to this wave's LDS region ----
#pragma unroll
    for (int mi = 0; mi < 2; mi++) {
      float rmax[4] = {NEG, NEG, NEG, NEG};
#pragma unroll
      for (int ni = 0; ni < 8; ni++) {
        if (ni <= nlim) {
#pragma unroll
          for (int r = 0; r < 4; r++) {
            int t_abs = qw0 + mi * 16 + quad * 4 + r;
            int s_abs = s0 + ni * 16 + l16;
            float v = (s_abs > t_abs) ? NEG : sacc[mi][ni][r] * scale;
            sacc[mi][ni][r] = v;
            rmax[r] = fmaxf(rmax[r], v);
          }
        }
      }
#pragma unroll
      for (int r = 0; r < 4; r++)
#pragma unroll
        for (int sh = 1; sh < 16; sh <<= 1)
          rmax[r] = fmaxf(rmax[r], __shfl_xor(rmax[r], sh));

      float alpha[4], rsum[4];
#pragma unroll
      for (int r = 0; r < 4; r++) {
        float mnew = fmaxf(mrow[mi][r], rmax[r]);
        alpha[r] = __expf(mrow[mi][r] - mnew);
        mrow[mi][r] = mnew;
        rsum[r] = 0.f;
      }
#pragma unroll
      for (int ni = 0; ni < 8; ni++) {
        if (ni <= nlim) {
#pragma unroll
          for (int r = 0; r < 4; r++) {
            float p = __expf(sacc[mi][ni][r] - mrow[mi][r]);   // masked -> exp(-inf)=0
            rsum[r] += p;
            Pw[(mi * 16 + quad * 4 + r) * 136 + ni * 16 + l16] = f2bf(p);
          }
        }
      }
#pragma unroll
      for (int r = 0; r < 4; r++) {
#pragma unroll
        for (int sh = 1; sh < 16; sh <<= 1) rsum[r] += __shfl_xor(rsum[r], sh);
        lrow[mi][r] = lrow[mi][r] * alpha[r] + rsum[r];
      }
#pragma unroll
      for (int di = 0; di < 6; di++)
#pragma unroll
        for (int r = 0; r < 4; r++) acc_o[mi][di][r] *= alpha[r];
    }

    // ---- O += P V  (P read from own wave's LDS: no barrier needed, lgkmcnt orders it) ----
#pragma unroll
    for (int kc = 0; kc < 4; kc++) {
      if (kc <= klim) {
        bf16x8 ap0 = *(const bf16x8*)&Pw[l16 * 136 + kc * 32 + quad * 8];
        bf16x8 ap1 = *(const bf16x8*)&Pw[(16 + l16) * 136 + kc * 32 + quad * 8];
#pragma unroll
        for (int di = 0; di < 6; di++) {
          bf16x8 bv = *(const bf16x8*)&Vsm[(di * 16 + l16) * 136 + kc * 32 + quad * 8];
          acc_o[0][di] = __builtin_amdgcn_mfma_f32_16x16x32_bf16(ap0, bv, acc_o[0][di], 0, 0, 0);
          acc_o[1][di] = __builtin_amdgcn_mfma_f32_16x16x32_bf16(ap1, bv, acc_o[1][di], 0, 0, 0);
        }
      }
    }
  }

#pragma unroll
  for (int mi = 0; mi < 2; mi++) {
#pragma unroll
    for (int r = 0; r < 4; r++) {
      float linv = 1.f / lrow[mi][r];
      int t = qw0 + mi * 16 + quad * 4 + r;
#pragma unroll
      for (int di = 0; di < 6; di++) {
        int d = di * 16 + l16;
        y[(b * Tz + t) * Cz + h * Dz + d] = f2bf(acc_o[mi][di][r] * linv);
      }
    }
  }
}

// ---- workspace layout (bytes) ----
#define OFF_XB   0u
#define OFF_WAT  12582912u            // 8192*768*2
#define OFF_WPT  16121856u            // + 2304*768*2
#define OFF_QKV  17301504u            // + 768*768*2
#define OFF_Y    55050240u            // + 3*64*1024*96*2

extern "C" void kernel_launch(void* const* d_in, const int* in_sizes, int n_in,
                              void* d_out, int out_size, void* d_ws, size_t ws_size,
                              hipStream_t stream) {
  const float* x  = (const float*)d_in[0];
  const float* Wa = (const float*)d_in[1];
  const float* Wp = (const float*)d_in[2];
  float* out = (float*)d_out;
  uint8_t* ws = (uint8_t*)d_ws;
  unsigned short* xb  = (unsigned short*)(ws + OFF_XB);
  unsigned short* Wat = (unsigned short*)(ws + OFF_WAT);
  unsigned short* Wpt = (unsigned short*)(ws + OFF_WPT);
  unsigned short* qkv = (unsigned short*)(ws + OFF_QKV);
  unsigned short* y   = (unsigned short*)(ws + OFF_Y);

  cast_f32_bf16<<<6144, 256, 0, stream>>>(x, xb);
  transpose_cast<<<dim3(36, 12), 256, 0, stream>>>(Wa, Wat, 768, 2304);
  transpose_cast<<<dim3(12, 12), 256, 0, stream>>>(Wp, Wpt, 768, 768);
  gemm128<0><<<dim3(64, 18), 256, 0, stream>>>(xb, Wat, qkv, nullptr);
  attn<<<dim3(64, 8), 256, 0, stream>>>(qkv, y);
  gemm128<1><<<dim3(64, 6), 256, 0, stream>>>(y, Wpt, nullptr, out);
}